// Round 1
// baseline (118.550 us; speedup 1.0000x reference)
//
#include <hip/hip_runtime.h>

// SWAP gate on qudits (DIM=2, WIRES=12, C=0, T=1): U is a permutation matrix
// swapping row-index bits 11 and 10 of the 4096-row index; rows are 4 KiB
// contiguous, so in float4-index space (2^20 per plane) the swap hits bits
// 18 and 19. out[plane][w] = x[plane][w with bits18,19 swapped].
//
// v2: non-temporal LOADS as well as stores (data is touched exactly once —
// bypass cache pollution), and 2 float4 per quadrant per thread (8 ld + 8 st,
// 256 B/thread) for deeper memory-level parallelism. Grid: 1024 blocks
// (2^18 threads), 16 waves/CU. Second element at base + 2^17 keeps every
// VMEM instruction's 64 lanes inside one contiguous 1 KiB segment.

typedef float v4f __attribute__((ext_vector_type(4)));

#define PLANE4 (1u << 20)   // float4 per plane (2^20)
#define QUAD4  (1u << 18)   // float4 per quadrant
#define HALF4  (1u << 17)   // per-thread stride within a quadrant

__global__ __launch_bounds__(256) void swap_perm_kernel(
    const v4f* __restrict__ xr,
    const v4f* __restrict__ xi,
    v4f* __restrict__ out)
{
    const unsigned g     = blockIdx.x * 256u + threadIdx.x;  // [0, 2^18)
    const unsigned plane = g >> 17;                          // 0 = real, 1 = imag
    const unsigned base  = g & (HALF4 - 1u);                 // [0, 2^17)

    const v4f* __restrict__ in = plane ? xi : xr;
    v4f* __restrict__ o = out + plane * PLANE4;

    // 8 independent loads in flight, then 8 streaming stores.
    v4f a0 = __builtin_nontemporal_load(in + base + 0u * QUAD4);
    v4f a1 = __builtin_nontemporal_load(in + base + 1u * QUAD4);
    v4f a2 = __builtin_nontemporal_load(in + base + 2u * QUAD4);
    v4f a3 = __builtin_nontemporal_load(in + base + 3u * QUAD4);
    v4f b0 = __builtin_nontemporal_load(in + base + HALF4 + 0u * QUAD4);
    v4f b1 = __builtin_nontemporal_load(in + base + HALF4 + 1u * QUAD4);
    v4f b2 = __builtin_nontemporal_load(in + base + HALF4 + 2u * QUAD4);
    v4f b3 = __builtin_nontemporal_load(in + base + HALF4 + 3u * QUAD4);

    __builtin_nontemporal_store(a0, o + base + 0u * QUAD4);
    __builtin_nontemporal_store(a2, o + base + 1u * QUAD4);  // dest 01 <- src 10
    __builtin_nontemporal_store(a1, o + base + 2u * QUAD4);  // dest 10 <- src 01
    __builtin_nontemporal_store(a3, o + base + 3u * QUAD4);
    __builtin_nontemporal_store(b0, o + base + HALF4 + 0u * QUAD4);
    __builtin_nontemporal_store(b2, o + base + HALF4 + 1u * QUAD4);
    __builtin_nontemporal_store(b1, o + base + HALF4 + 2u * QUAD4);
    __builtin_nontemporal_store(b3, o + base + HALF4 + 3u * QUAD4);
}

extern "C" void kernel_launch(void* const* d_in, const int* in_sizes, int n_in,
                              void* d_out, int out_size, void* d_ws, size_t ws_size,
                              hipStream_t stream) {
    const v4f* xr = (const v4f*)d_in[0];
    const v4f* xi = (const v4f*)d_in[1];
    // d_in[2] is U — intentionally unused: the permutation is hardcoded.
    v4f* out = (v4f*)d_out;

    swap_perm_kernel<<<(1u << 18) / 256, 256, 0, stream>>>(xr, xi, out);
}